// Round 1
// baseline (982.843 us; speedup 1.0000x reference)
//
#include <hip/hip_runtime.h>

// Fused MHA block: QKV proj -> softmax attention -> out proj.
// fp32 I/O; all GEMMs via split-bf16 (hi+lo) MFMA emulation:
//   A*B ~= Ah*Bh + Al*Bh + Ah*Bl   (error ~2^-16 rel, well under 5.2e-3 absmax)
// B=4, N=2048, D=1024, H=16, Dh=64, SCALE=0.125 (exact pow2, folded into Q).

typedef __attribute__((ext_vector_type(8))) short bf8v;   // 8 bf16 bit-patterns (4 VGPR)
typedef __attribute__((ext_vector_type(4))) short bf4v;
typedef __attribute__((ext_vector_type(4))) float f32x4;

#define DEVINL __device__ __forceinline__

DEVINL unsigned short f2bf(float x){            // RNE fp32 -> bf16 bits
    unsigned int u = __float_as_uint(x);
    return (unsigned short)((u + 0x7FFFu + ((u >> 16) & 1u)) >> 16);
}
DEVINL float bf2f(unsigned short b){ return __uint_as_float(((unsigned int)b) << 16); }

// ---------------------------------------------------------------- split (row-major)
__global__ __launch_bounds__(256) void split_rm(const float* __restrict__ in,
        unsigned short* __restrict__ oh, unsigned short* __restrict__ ol, int n4){
    int i = blockIdx.x * 256 + threadIdx.x;
    if (i >= n4) return;
    float4 v = reinterpret_cast<const float4*>(in)[i];
    float vv[4] = {v.x, v.y, v.z, v.w};
    bf4v h, l;
#pragma unroll
    for (int j = 0; j < 4; ++j){
        unsigned short hb = f2bf(vv[j]);
        h[j] = (short)hb;
        l[j] = (short)f2bf(vv[j] - bf2f(hb));
    }
    *reinterpret_cast<bf4v*>(oh + (size_t)i * 4) = h;
    *reinterpret_cast<bf4v*>(ol + (size_t)i * 4) = l;
}

// ------------------------------------------------- split + transpose (weights -> [N][K])
__global__ __launch_bounds__(256) void transpose_split(const float* __restrict__ in,
        unsigned short* __restrict__ oh, unsigned short* __restrict__ ol,
        int K, int N){                       // in: [K][N] fp32 ; out: [N][K] bf16 hi/lo
    __shared__ float tile[32][33];
    int n0 = blockIdx.x * 32, k0 = blockIdx.y * 32;
    int c = threadIdx.x & 31, r0 = threadIdx.x >> 5;
#pragma unroll
    for (int j = 0; j < 4; ++j){
        int r = r0 + j * 8;
        tile[r][c] = in[(size_t)(k0 + r) * N + n0 + c];
    }
    __syncthreads();
#pragma unroll
    for (int j = 0; j < 4; ++j){
        int r = r0 + j * 8;                  // output-row offset (n); c = k offset
        float v = tile[c][r];                // in[k0+c][n0+r]
        unsigned short hb = f2bf(v);
        size_t o = (size_t)(n0 + r) * K + k0 + c;
        oh[o] = hb; ol[o] = f2bf(v - bf2f(hb));
    }
}

// ---------------------------------------------------------------- split-bf16 GEMM
// C[M,N] = A[M,1024-per-plane] * B^T-stored[N,1024] over K' = 3072 (3 plane passes).
// EPI 0: QKV epilogue (scatter Q,K row-major + V transposed, Q pre-scaled 0.125)
// EPI 1: fp32 C write + bias
template<int EPI>
__global__ __launch_bounds__(256) void gemm3k(
    const unsigned short* __restrict__ Ah, const unsigned short* __restrict__ Al,
    const unsigned short* __restrict__ Bh, const unsigned short* __restrict__ Bl,
    const float* __restrict__ bias, float* __restrict__ outf,
    unsigned short* __restrict__ Qh, unsigned short* __restrict__ Ql,
    unsigned short* __restrict__ Kh, unsigned short* __restrict__ Kl,
    unsigned short* __restrict__ Vth, unsigned short* __restrict__ Vtl)
{
    __shared__ unsigned short Alds[128][40];   // +8 pad: 80B rows -> 2-way (free)
    __shared__ unsigned short Blds[128][40];
    const int t = threadIdx.x;
    const int l = t & 63, g = l >> 4, wv = t >> 6;
    const int wr = wv >> 1, wc = wv & 1;
    const int bm = blockIdx.y * 128, bn = blockIdx.x * 128;
    const int srow = t >> 2, scol = (t & 3) * 8;

    f32x4 acc[4][4] = {};
    bf8v ra[2], rb[2];
    // prefetch tile 0 (plane 0, klocal 0)
#pragma unroll
    for (int j = 0; j < 2; ++j){
        ra[j] = *reinterpret_cast<const bf8v*>(Ah + (size_t)(bm + srow + j*64) * 1024 + scol);
        rb[j] = *reinterpret_cast<const bf8v*>(Bh + (size_t)(bn + srow + j*64) * 1024 + scol);
    }
#pragma unroll 1
    for (int kt = 0; kt < 96; ++kt){
        __syncthreads();
#pragma unroll
        for (int j = 0; j < 2; ++j){
            *reinterpret_cast<bf8v*>(&Alds[srow + j*64][scol]) = ra[j];
            *reinterpret_cast<bf8v*>(&Blds[srow + j*64][scol]) = rb[j];
        }
        __syncthreads();
        if (kt + 1 < 96){
            int p = (kt + 1) >> 5;
            const unsigned short* Ap = (p == 1) ? Al : Ah;
            const unsigned short* Bp = (p == 2) ? Bl : Bh;
            int klocal = ((kt + 1) & 31) * 32;
#pragma unroll
            for (int j = 0; j < 2; ++j){
                ra[j] = *reinterpret_cast<const bf8v*>(Ap + (size_t)(bm + srow + j*64)*1024 + klocal + scol);
                rb[j] = *reinterpret_cast<const bf8v*>(Bp + (size_t)(bn + srow + j*64)*1024 + klocal + scol);
            }
        }
        bf8v af[4], bfv[4];
#pragma unroll
        for (int mf = 0; mf < 4; ++mf)
            af[mf] = *reinterpret_cast<const bf8v*>(&Alds[wr*64 + mf*16 + (l & 15)][g*8]);
#pragma unroll
        for (int nf = 0; nf < 4; ++nf)
            bfv[nf] = *reinterpret_cast<const bf8v*>(&Blds[wc*64 + nf*16 + (l & 15)][g*8]);
#pragma unroll
        for (int mf = 0; mf < 4; ++mf)
#pragma unroll
            for (int nf = 0; nf < 4; ++nf)
                acc[mf][nf] = __builtin_amdgcn_mfma_f32_16x16x32_bf16(af[mf], bfv[nf], acc[mf][nf], 0, 0, 0);
    }
    // epilogue  (C/D layout: col = lane&15, row = (lane>>4)*4 + r)
#pragma unroll
    for (int mf = 0; mf < 4; ++mf)
#pragma unroll
    for (int nf = 0; nf < 4; ++nf)
#pragma unroll
    for (int r = 0; r < 4; ++r){
        int n = bn + wc*64 + nf*16 + (l & 15);
        int m = bm + wr*64 + mf*16 + g*4 + r;
        float v = acc[mf][nf][r] + bias[n];
        if (EPI == 0){
            int sec = n >> 10;                       // 0=Q 1=K 2=V (block-uniform)
            int nn = n & 1023, hh = nn >> 6, dh = nn & 63;
            int bb = m >> 11, tok = m & 2047;
            if (sec == 0) v *= 0.125f;               // fold SCALE into Q (exact)
            unsigned short hb = f2bf(v), lb = f2bf(v - bf2f(hb));
            if (sec == 2){
                size_t o = ((size_t)((bb*16 + hh)*64 + dh)) * 2048 + tok;  // V^T
                Vth[o] = hb; Vtl[o] = lb;
            } else {
                size_t o = ((size_t)((bb*16 + hh)*2048 + tok)) * 64 + dh;
                if (sec == 0){ Qh[o] = hb; Ql[o] = lb; }
                else         { Kh[o] = hb; Kl[o] = lb; }
            }
        } else {
            outf[(size_t)m * 1024 + n] = v;
        }
    }
}

// ---------------------------------------------------------------- flash attention
// Swapped-operand: S^T = mfma(K,Q) so q sits in lane&15 -> softmax state, P-frags,
// and O^T = mfma(V^T, P^T) are all lane-local. No LDS, no barriers in KV loop.
__global__ __launch_bounds__(256) void attn(
    const unsigned short* __restrict__ Qh, const unsigned short* __restrict__ Ql,
    const unsigned short* __restrict__ Kh, const unsigned short* __restrict__ Kl,
    const unsigned short* __restrict__ Vth, const unsigned short* __restrict__ Vtl,
    unsigned short* __restrict__ Oh, unsigned short* __restrict__ Ol)
{
    const int t = threadIdx.x, l = t & 63, g = l >> 4, wv = t >> 6;
    const int bid = blockIdx.x;
    const int qt = bid & 15, hh = (bid >> 4) & 15, bb = bid >> 8;
    const size_t bh = (size_t)(bb * 16 + hh);
    const int q0 = qt * 128 + wv * 32;       // each wave owns 32 q-rows

    bf8v qf[2][2][2];                        // [nf][hi/lo][ks]  (Q pre-scaled)
#pragma unroll
    for (int nf = 0; nf < 2; ++nf){
        int q = q0 + nf*16 + (l & 15);
        size_t ro = (bh * 2048 + q) * 64 + g * 8;
#pragma unroll
        for (int ks = 0; ks < 2; ++ks){
            qf[nf][0][ks] = *reinterpret_cast<const bf8v*>(Qh + ro + ks*32);
            qf[nf][1][ks] = *reinterpret_cast<const bf8v*>(Ql + ro + ks*32);
        }
    }
    f32x4 ot[4][2] = {};                     // O^T acc: [mf=dh-tile][nf=q-tile]
    float m_run[2] = {-1e30f, -1e30f};
    float l_run[2] = {0.f, 0.f};

#pragma unroll 1
    for (int it = 0; it < 64; ++it){
        int kv0 = it * 32;
        bf8v kf[2][2][2];                    // [mf=kv-tile][hi/lo][ks]
#pragma unroll
        for (int mf = 0; mf < 2; ++mf){
            int kv = kv0 + mf*16 + (l & 15);
            size_t ro = (bh * 2048 + kv) * 64 + g * 8;
#pragma unroll
            for (int ks = 0; ks < 2; ++ks){
                kf[mf][0][ks] = *reinterpret_cast<const bf8v*>(Kh + ro + ks*32);
                kf[mf][1][ks] = *reinterpret_cast<const bf8v*>(Kl + ro + ks*32);
            }
        }
        f32x4 s[2][2] = {};                  // S^T frags: row=kv, col=q
#pragma unroll
        for (int mf = 0; mf < 2; ++mf)
#pragma unroll
        for (int nf = 0; nf < 2; ++nf)
#pragma unroll
        for (int ks = 0; ks < 2; ++ks){
            s[mf][nf] = __builtin_amdgcn_mfma_f32_16x16x32_bf16(kf[mf][0][ks], qf[nf][0][ks], s[mf][nf], 0,0,0);
            s[mf][nf] = __builtin_amdgcn_mfma_f32_16x16x32_bf16(kf[mf][1][ks], qf[nf][0][ks], s[mf][nf], 0,0,0);
            s[mf][nf] = __builtin_amdgcn_mfma_f32_16x16x32_bf16(kf[mf][0][ks], qf[nf][1][ks], s[mf][nf], 0,0,0);
        }
        // online softmax per q-col (lane-local; reduce across the 4 lane-groups)
        bf8v ph[2], pl[2];
        float cfac[2];
#pragma unroll
        for (int nf = 0; nf < 2; ++nf){
            float tm = s[0][nf][0];
#pragma unroll
            for (int mf = 0; mf < 2; ++mf)
#pragma unroll
                for (int r = 0; r < 4; ++r) tm = fmaxf(tm, s[mf][nf][r]);
            tm = fmaxf(tm, __shfl_xor(tm, 16));
            tm = fmaxf(tm, __shfl_xor(tm, 32));
            float mn = fmaxf(m_run[nf], tm);
            float c = __expf(m_run[nf] - mn);
            float p[2][4], rs = 0.f;
#pragma unroll
            for (int mf = 0; mf < 2; ++mf)
#pragma unroll
            for (int r = 0; r < 4; ++r){
                p[mf][r] = __expf(s[mf][nf][r] - mn);
                rs += p[mf][r];
            }
            rs += __shfl_xor(rs, 16);
            rs += __shfl_xor(rs, 32);
            l_run[nf] = l_run[nf] * c + rs;
            m_run[nf] = mn;
            cfac[nf] = c;
            // P^T B-frag, k-slot i -> kv sigma(g,i) = (i<4 ? 4g+i : 16+4g+i-4)
#pragma unroll
            for (int i = 0; i < 8; ++i){
                float pv = p[i >> 2][i & 3];
                unsigned short hb = f2bf(pv);
                ph[nf][i] = (short)hb;
                pl[nf][i] = (short)f2bf(pv - bf2f(hb));
            }
        }
#pragma unroll
        for (int mf = 0; mf < 4; ++mf)
#pragma unroll
            for (int nf = 0; nf < 2; ++nf)
#pragma unroll
                for (int r = 0; r < 4; ++r) ot[mf][nf][r] *= cfac[nf];
        // V^T A-frags with matching k-permutation: reads at kv0+4g and kv0+16+4g
#pragma unroll
        for (int mf = 0; mf < 4; ++mf){
            int dh = mf*16 + (l & 15);
            size_t ro = (bh * 64 + dh) * 2048 + kv0 + g * 4;
            bf4v a0 = *reinterpret_cast<const bf4v*>(Vth + ro);
            bf4v a1 = *reinterpret_cast<const bf4v*>(Vth + ro + 16);
            bf4v b0 = *reinterpret_cast<const bf4v*>(Vtl + ro);
            bf4v b1 = *reinterpret_cast<const bf4v*>(Vtl + ro + 16);
            bf8v vh, vl;
#pragma unroll
            for (int i = 0; i < 4; ++i){ vh[i] = a0[i]; vh[i+4] = a1[i]; vl[i] = b0[i]; vl[i+4] = b1[i]; }
#pragma unroll
            for (int nf = 0; nf < 2; ++nf){
                ot[mf][nf] = __builtin_amdgcn_mfma_f32_16x16x32_bf16(vh, ph[nf], ot[mf][nf], 0,0,0);
                ot[mf][nf] = __builtin_amdgcn_mfma_f32_16x16x32_bf16(vh, pl[nf], ot[mf][nf], 0,0,0);
                ot[mf][nf] = __builtin_amdgcn_mfma_f32_16x16x32_bf16(vl, ph[nf], ot[mf][nf], 0,0,0);
            }
        }
    }
    // finalize: O = O^T / l, write att hi/lo (input planes of proj GEMM)
#pragma unroll
    for (int nf = 0; nf < 2; ++nf){
        float inv = 1.f / l_run[nf];
        int tok = q0 + nf*16 + (l & 15);
#pragma unroll
        for (int mf = 0; mf < 4; ++mf){
            bf4v hv, lv;
#pragma unroll
            for (int r = 0; r < 4; ++r){
                float v = ot[mf][nf][r] * inv;
                unsigned short hb = f2bf(v);
                hv[r] = (short)hb;
                lv[r] = (short)f2bf(v - bf2f(hb));
            }
            size_t o = ((size_t)(bb * 2048 + tok)) * 1024 + hh*64 + mf*16 + g*4;
            *reinterpret_cast<bf4v*>(Oh + o) = hv;
            *reinterpret_cast<bf4v*>(Ol + o) = lv;
        }
    }
}

// ---------------------------------------------------------------- launch
extern "C" void kernel_launch(void* const* d_in, const int* in_sizes, int n_in,
                              void* d_out, int out_size, void* d_ws, size_t ws_size,
                              hipStream_t stream) {
    (void)in_sizes; (void)n_in; (void)out_size; (void)ws_size;
    const float* x      = (const float*)d_in[0];
    const float* w_qkv  = (const float*)d_in[1];
    const float* b_qkv  = (const float*)d_in[2];
    const float* w_proj = (const float*)d_in[3];
    const float* b_proj = (const float*)d_in[4];
    float* out = (float*)d_out;

    char* w = (char*)d_ws;
    // ws layout (bytes); total 151 MB. X region is reused for attention output.
    unsigned short* XH  = (unsigned short*)(w + 0);           // 16.78 MB  [8192][1024]
    unsigned short* XL  = (unsigned short*)(w + 16777216);
    unsigned short* WQH = (unsigned short*)(w + 33554432);    // 6.29 MB   [3072][1024] (W^T)
    unsigned short* WQL = (unsigned short*)(w + 39845888);
    unsigned short* WPH = (unsigned short*)(w + 46137344);    // 2.10 MB   [1024][1024] (W^T)
    unsigned short* WPL = (unsigned short*)(w + 48234496);
    unsigned short* QH  = (unsigned short*)(w + 50331648);    // 16.78 MB  [B,H,2048,64]
    unsigned short* QL  = (unsigned short*)(w + 67108864);
    unsigned short* KH  = (unsigned short*)(w + 83886080);
    unsigned short* KL  = (unsigned short*)(w + 100663296);
    unsigned short* VTH = (unsigned short*)(w + 117440512);   // 16.78 MB  [B,H,64,2048]
    unsigned short* VTL = (unsigned short*)(w + 134217728);
    unsigned short* ATH = XH;                                 // att out aliases X
    unsigned short* ATL = XL;

    split_rm<<<8192, 256, 0, stream>>>(x, XH, XL, 2097152);
    transpose_split<<<dim3(96, 32), 256, 0, stream>>>(w_qkv, WQH, WQL, 1024, 3072);
    transpose_split<<<dim3(32, 32), 256, 0, stream>>>(w_proj, WPH, WPL, 1024, 1024);
    gemm3k<0><<<dim3(24, 64), 256, 0, stream>>>(XH, XL, WQH, WQL, b_qkv, nullptr,
                                                QH, QL, KH, KL, VTH, VTL);
    attn<<<1024, 256, 0, stream>>>(QH, QL, KH, KL, VTH, VTL, ATH, ATL);
    gemm3k<1><<<dim3(8, 64), 256, 0, stream>>>(ATH, ATL, WPH, WPL, b_proj, out,
                                               nullptr, nullptr, nullptr, nullptr, nullptr, nullptr);
}

// Round 2
// 779.367 us; speedup vs baseline: 1.2611x; 1.2611x over previous
//
#include <hip/hip_runtime.h>

// Fused MHA block: QKV proj -> softmax attention -> out proj.
// fp32 I/O; all GEMMs via split-bf16 (hi+lo) MFMA emulation:
//   A*B ~= Ah*Bh + Al*Bh + Ah*Bl   (error ~2^-16 rel, well under 5.2e-3 absmax)
// B=4, N=2048, D=1024, H=16, Dh=64. SCALE*log2e folded into Q so softmax
// runs in exp2 domain (v_exp_f32 native).

typedef __attribute__((ext_vector_type(8))) short bf8v;   // 8 bf16 bit-patterns (4 VGPR)
typedef __attribute__((ext_vector_type(4))) short bf4v;
typedef __attribute__((ext_vector_type(4))) float f32x4;

#define DEVINL __device__ __forceinline__

DEVINL unsigned short f2bf(float x){            // RNE fp32 -> bf16 bits
    unsigned int u = __float_as_uint(x);
    return (unsigned short)((u + 0x7FFFu + ((u >> 16) & 1u)) >> 16);
}
DEVINL float bf2f(unsigned short b){ return __uint_as_float(((unsigned int)b) << 16); }

union BV { bf8v v; unsigned int u[4]; };

// ---------------------------------------------------------------- split (row-major)
__global__ __launch_bounds__(256) void split_rm(const float* __restrict__ in,
        unsigned short* __restrict__ oh, unsigned short* __restrict__ ol, int n4){
    int i = blockIdx.x * 256 + threadIdx.x;
    if (i >= n4) return;
    float4 v = reinterpret_cast<const float4*>(in)[i];
    float vv[4] = {v.x, v.y, v.z, v.w};
    bf4v h, l;
#pragma unroll
    for (int j = 0; j < 4; ++j){
        unsigned short hb = f2bf(vv[j]);
        h[j] = (short)hb;
        l[j] = (short)f2bf(vv[j] - bf2f(hb));
    }
    *reinterpret_cast<bf4v*>(oh + (size_t)i * 4) = h;
    *reinterpret_cast<bf4v*>(ol + (size_t)i * 4) = l;
}

// ------------------------------------------------- split + transpose (weights -> [N][K])
__global__ __launch_bounds__(256) void transpose_split(const float* __restrict__ in,
        unsigned short* __restrict__ oh, unsigned short* __restrict__ ol,
        int K, int N){                       // in: [K][N] fp32 ; out: [N][K] bf16 hi/lo
    __shared__ float tile[32][33];
    int n0 = blockIdx.x * 32, k0 = blockIdx.y * 32;
    int c = threadIdx.x & 31, r0 = threadIdx.x >> 5;
#pragma unroll
    for (int j = 0; j < 4; ++j){
        int r = r0 + j * 8;
        tile[r][c] = in[(size_t)(k0 + r) * N + n0 + c];
    }
    __syncthreads();
#pragma unroll
    for (int j = 0; j < 4; ++j){
        int r = r0 + j * 8;                  // output-row offset (n); c = k offset
        float v = tile[c][r];                // in[k0+c][n0+r]
        unsigned short hb = f2bf(v);
        size_t o = (size_t)(n0 + r) * K + k0 + c;
        oh[o] = hb; ol[o] = f2bf(v - bf2f(hb));
    }
}

// ---------------------------------------------------------------- split-bf16 GEMM
// C[M,N] = A[M,1024-per-plane] * B^T-stored[N,1024] over K' = 3072 (3 plane passes).
// EPI 0: QKV epilogue (scatter Q (pre-scaled 0.125*log2e), K, V^T k-permuted)
// EPI 1: fp32 C write + bias
template<int EPI>
__global__ __launch_bounds__(256) void gemm3k(
    const unsigned short* __restrict__ Ah, const unsigned short* __restrict__ Al,
    const unsigned short* __restrict__ Bh, const unsigned short* __restrict__ Bl,
    const float* __restrict__ bias, float* __restrict__ outf,
    unsigned short* __restrict__ Qh, unsigned short* __restrict__ Ql,
    unsigned short* __restrict__ Kh, unsigned short* __restrict__ Kl,
    unsigned short* __restrict__ Vth, unsigned short* __restrict__ Vtl)
{
    __shared__ unsigned short Alds[128][40];   // +8 pad: 80B rows -> 2-way (free)
    __shared__ unsigned short Blds[128][40];
    const int t = threadIdx.x;
    const int l = t & 63, g = l >> 4, wv = t >> 6;
    const int wr = wv >> 1, wc = wv & 1;
    const int bm = blockIdx.y * 128, bn = blockIdx.x * 128;
    const int srow = t >> 2, scol = (t & 3) * 8;

    f32x4 acc[4][4] = {};
    bf8v ra[2], rb[2];
    // prefetch tile 0 (plane 0, klocal 0)
#pragma unroll
    for (int j = 0; j < 2; ++j){
        ra[j] = *reinterpret_cast<const bf8v*>(Ah + (size_t)(bm + srow + j*64) * 1024 + scol);
        rb[j] = *reinterpret_cast<const bf8v*>(Bh + (size_t)(bn + srow + j*64) * 1024 + scol);
    }
#pragma unroll 1
    for (int kt = 0; kt < 96; ++kt){
        __syncthreads();
#pragma unroll
        for (int j = 0; j < 2; ++j){
            *reinterpret_cast<bf8v*>(&Alds[srow + j*64][scol]) = ra[j];
            *reinterpret_cast<bf8v*>(&Blds[srow + j*64][scol]) = rb[j];
        }
        __syncthreads();
        if (kt + 1 < 96){
            int p = (kt + 1) >> 5;
            const unsigned short* Ap = (p == 1) ? Al : Ah;
            const unsigned short* Bp = (p == 2) ? Bl : Bh;
            int klocal = ((kt + 1) & 31) * 32;
#pragma unroll
            for (int j = 0; j < 2; ++j){
                ra[j] = *reinterpret_cast<const bf8v*>(Ap + (size_t)(bm + srow + j*64)*1024 + klocal + scol);
                rb[j] = *reinterpret_cast<const bf8v*>(Bp + (size_t)(bn + srow + j*64)*1024 + klocal + scol);
            }
        }
        bf8v af[4], bfv[4];
#pragma unroll
        for (int mf = 0; mf < 4; ++mf)
            af[mf] = *reinterpret_cast<const bf8v*>(&Alds[wr*64 + mf*16 + (l & 15)][g*8]);
#pragma unroll
        for (int nf = 0; nf < 4; ++nf)
            bfv[nf] = *reinterpret_cast<const bf8v*>(&Blds[wc*64 + nf*16 + (l & 15)][g*8]);
#pragma unroll
        for (int mf = 0; mf < 4; ++mf)
#pragma unroll
            for (int nf = 0; nf < 4; ++nf)
                acc[mf][nf] = __builtin_amdgcn_mfma_f32_16x16x32_bf16(af[mf], bfv[nf], acc[mf][nf], 0, 0, 0);
    }
    // epilogue  (C/D layout: col = lane&15, row = (lane>>4)*4 + r)
#pragma unroll
    for (int mf = 0; mf < 4; ++mf)
#pragma unroll
    for (int nf = 0; nf < 4; ++nf)
#pragma unroll
    for (int r = 0; r < 4; ++r){
        int n = bn + wc*64 + nf*16 + (l & 15);
        int m = bm + wr*64 + mf*16 + g*4 + r;
        float v = acc[mf][nf][r] + bias[n];
        if (EPI == 0){
            int sec = n >> 10;                       // 0=Q 1=K 2=V (block-uniform)
            int nn = n & 1023, hh = nn >> 6, dh = nn & 63;
            int bb = m >> 11, tok = m & 2047;
            if (sec == 0) v *= 0.18033688011112042f; // SCALE * log2(e) (exp2 domain)
            unsigned short hb = f2bf(v), lb = f2bf(v - bf2f(hb));
            if (sec == 2){
                // k-slot permuted V^T column so attn PV A-frag is one contiguous 16B:
                // j=tok&31 -> ((j>>2)&3)*8 + (j&3) + ((j>>4)&1)*4
                int tok2 = (tok & ~31) | (((tok >> 2) & 3) << 3) | (tok & 3) | (((tok >> 4) & 1) << 2);
                size_t o = ((size_t)((bb*16 + hh)*64 + dh)) * 2048 + tok2;
                Vth[o] = hb; Vtl[o] = lb;
            } else {
                size_t o = ((size_t)((bb*16 + hh)*2048 + tok)) * 64 + dh;
                if (sec == 0){ Qh[o] = hb; Ql[o] = lb; }
                else         { Kh[o] = hb; Kl[o] = lb; }
            }
        } else {
            outf[(size_t)m * 1024 + n] = v;
        }
    }
}

// ---------------------------------------------------------------- flash attention
// Swapped-operand: S^T = mfma(K,Q), q in lane&15 -> softmax + P + O^T all lane-local.
// No LDS/barriers. K double-buffered (prefetch it+1); V issued early, consumed after
// softmax. exp2-domain softmax, defer-max THR=8, trunc-hi/lo P split via v_perm.
template<int CUR>
DEVINL void attn_step(int it,
    const unsigned short* __restrict__ Kbh, const unsigned short* __restrict__ Kbl,
    const unsigned short* __restrict__ Vbh, const unsigned short* __restrict__ Vbl,
    unsigned koff, unsigned voff,
    bf8v (&kh_)[2][2][2], bf8v (&kl_)[2][2][2],
    bf8v (&vh_)[4], bf8v (&vl_)[4],
    const bf8v (&qh_)[2][2], const bf8v (&ql_)[2][2],
    f32x4 (&ot)[4][2], float (&m_run)[2], float (&l_run)[2])
{
    constexpr int NXT = CUR ^ 1;
    // V[it] loads (single buffer; consumed ~400cyc later, after softmax)
    {
        unsigned vo = voff + (unsigned)it * 32u;
#pragma unroll
        for (int mf = 0; mf < 4; ++mf){
            vh_[mf] = *reinterpret_cast<const bf8v*>(Vbh + vo + mf*32768u);
            vl_[mf] = *reinterpret_cast<const bf8v*>(Vbl + vo + mf*32768u);
        }
    }
    // K[it+1] prefetch into the other buffer
    {
        unsigned ko = koff + (unsigned)(it + 1) * 2048u;
#pragma unroll
        for (int mf = 0; mf < 2; ++mf)
#pragma unroll
        for (int ks = 0; ks < 2; ++ks){
            kh_[NXT][mf][ks] = *reinterpret_cast<const bf8v*>(Kbh + ko + mf*1024 + ks*32);
            kl_[NXT][mf][ks] = *reinterpret_cast<const bf8v*>(Kbl + ko + mf*1024 + ks*32);
        }
    }
    // S^T = K*Q (exp2-scaled), 3-term split
    f32x4 s[2][2] = {};
#pragma unroll
    for (int mf = 0; mf < 2; ++mf)
#pragma unroll
    for (int nf = 0; nf < 2; ++nf)
#pragma unroll
    for (int ks = 0; ks < 2; ++ks){
        s[mf][nf] = __builtin_amdgcn_mfma_f32_16x16x32_bf16(kh_[CUR][mf][ks], qh_[nf][ks], s[mf][nf], 0,0,0);
        s[mf][nf] = __builtin_amdgcn_mfma_f32_16x16x32_bf16(kl_[CUR][mf][ks], qh_[nf][ks], s[mf][nf], 0,0,0);
        s[mf][nf] = __builtin_amdgcn_mfma_f32_16x16x32_bf16(kh_[CUR][mf][ks], ql_[nf][ks], s[mf][nf], 0,0,0);
    }
    // online softmax, exp2 domain, defer-max (skip O rescale unless max grew > 8)
    float tm[2];
#pragma unroll
    for (int nf = 0; nf < 2; ++nf){
        float a = fmaxf(fmaxf(s[0][nf][0], s[0][nf][1]), fmaxf(s[0][nf][2], s[0][nf][3]));
        float b = fmaxf(fmaxf(s[1][nf][0], s[1][nf][1]), fmaxf(s[1][nf][2], s[1][nf][3]));
        float c = fmaxf(a, b);
        c = fmaxf(c, __shfl_xor(c, 16));
        c = fmaxf(c, __shfl_xor(c, 32));
        tm[nf] = c;
    }
    if (__any((tm[0] > m_run[0] + 8.f) || (tm[1] > m_run[1] + 8.f))){
#pragma unroll
        for (int nf = 0; nf < 2; ++nf){
            float mn = fmaxf(m_run[nf], tm[nf]);
            float c = __builtin_amdgcn_exp2f(m_run[nf] - mn);
            m_run[nf] = mn;
            l_run[nf] *= c;
#pragma unroll
            for (int mf = 0; mf < 4; ++mf)
#pragma unroll
            for (int r = 0; r < 4; ++r) ot[mf][nf][r] *= c;
        }
    }
    BV ph[2], pl[2];
#pragma unroll
    for (int nf = 0; nf < 2; ++nf){
        float p[8];
        float rs = 0.f;
#pragma unroll
        for (int mf = 0; mf < 2; ++mf)
#pragma unroll
        for (int r = 0; r < 4; ++r){
            float e = __builtin_amdgcn_exp2f(s[mf][nf][r] - m_run[nf]);
            p[mf*4 + r] = e;
            rs += e;
        }
        rs += __shfl_xor(rs, 16);
        rs += __shfl_xor(rs, 32);
        l_run[nf] += rs;
        // trunc-hi + exact-residual-lo, packed 2-at-a-time with v_perm
#pragma unroll
        for (int i = 0; i < 4; ++i){
            float p0 = p[2*i], p1 = p[2*i+1];
            float h0 = __uint_as_float(__float_as_uint(p0) & 0xFFFF0000u);
            float h1 = __uint_as_float(__float_as_uint(p1) & 0xFFFF0000u);
            ph[nf].u[i] = __builtin_amdgcn_perm(__float_as_uint(p1), __float_as_uint(p0), 0x07060302u);
            pl[nf].u[i] = __builtin_amdgcn_perm(__float_as_uint(p1 - h1), __float_as_uint(p0 - h0), 0x07060302u);
        }
    }
    // PV: O^T += V^T * P^T  (V pre-permuted in k-slots to match P ordering)
#pragma unroll
    for (int mf = 0; mf < 4; ++mf)
#pragma unroll
    for (int nf = 0; nf < 2; ++nf){
        ot[mf][nf] = __builtin_amdgcn_mfma_f32_16x16x32_bf16(vh_[mf], ph[nf].v, ot[mf][nf], 0,0,0);
        ot[mf][nf] = __builtin_amdgcn_mfma_f32_16x16x32_bf16(vh_[mf], pl[nf].v, ot[mf][nf], 0,0,0);
        ot[mf][nf] = __builtin_amdgcn_mfma_f32_16x16x32_bf16(vl_[mf], ph[nf].v, ot[mf][nf], 0,0,0);
    }
}

__global__ __launch_bounds__(256, 2) void attn(
    const unsigned short* __restrict__ Qh, const unsigned short* __restrict__ Ql,
    const unsigned short* __restrict__ Kh, const unsigned short* __restrict__ Kl,
    const unsigned short* __restrict__ Vth, const unsigned short* __restrict__ Vtl,
    unsigned short* __restrict__ Oh, unsigned short* __restrict__ Ol)
{
    const int t = threadIdx.x, l = t & 63, g = l >> 4, wv = t >> 6;
    const int bid = blockIdx.x;
    const int qt = bid & 15, hh = (bid >> 4) & 15, bb = bid >> 8;
    const int bh = bb * 16 + hh;
    const int q0 = qt * 128 + wv * 32;       // each wave owns 32 q-rows

    const unsigned short* Kbh = Kh  + (size_t)bh * 131072;
    const unsigned short* Kbl = Kl  + (size_t)bh * 131072;
    const unsigned short* Vbh = Vth + (size_t)bh * 131072;
    const unsigned short* Vbl = Vtl + (size_t)bh * 131072;

    const unsigned koff = (unsigned)((l & 15) * 64 + g * 8);
    const unsigned voff = (unsigned)((l & 15) * 2048 + g * 8);

    bf8v qh_[2][2], ql_[2][2];               // [nf][ks]  (Q pre-scaled by 0.125*log2e)
#pragma unroll
    for (int nf = 0; nf < 2; ++nf){
        size_t ro = ((size_t)bh * 2048 + q0 + nf*16 + (l & 15)) * 64 + g * 8;
#pragma unroll
        for (int ks = 0; ks < 2; ++ks){
            qh_[nf][ks] = *reinterpret_cast<const bf8v*>(Qh + ro + ks*32);
            ql_[nf][ks] = *reinterpret_cast<const bf8v*>(Ql + ro + ks*32);
        }
    }
    f32x4 ot[4][2] = {};
    float m_run[2] = {-1e30f, -1e30f};
    float l_run[2] = {0.f, 0.f};

    bf8v kh_[2][2][2], kl_[2][2][2];
    bf8v vh_[4], vl_[4];
    // prologue: K tile 0 -> buffer 0
#pragma unroll
    for (int mf = 0; mf < 2; ++mf)
#pragma unroll
    for (int ks = 0; ks < 2; ++ks){
        kh_[0][mf][ks] = *reinterpret_cast<const bf8v*>(Kbh + koff + mf*1024 + ks*32);
        kl_[0][mf][ks] = *reinterpret_cast<const bf8v*>(Kbl + koff + mf*1024 + ks*32);
    }
#pragma unroll 1
    for (int it = 0; it < 64; it += 2){
        attn_step<0>(it,     Kbh, Kbl, Vbh, Vbl, koff, voff, kh_, kl_, vh_, vl_, qh_, ql_, ot, m_run, l_run);
        attn_step<1>(it + 1, Kbh, Kbl, Vbh, Vbl, koff, voff, kh_, kl_, vh_, vl_, qh_, ql_, ot, m_run, l_run);
    }
    // finalize: O = O^T / l, write att hi/lo (input planes of proj GEMM)
#pragma unroll
    for (int nf = 0; nf < 2; ++nf){
        float inv = 1.f / l_run[nf];
        int tok = q0 + nf*16 + (l & 15);
#pragma unroll
        for (int mf = 0; mf < 4; ++mf){
            bf4v hv, lv;
#pragma unroll
            for (int r = 0; r < 4; ++r){
                float v = ot[mf][nf][r] * inv;
                unsigned short hb = f2bf(v);
                hv[r] = (short)hb;
                lv[r] = (short)f2bf(v - bf2f(hb));
            }
            size_t o = ((size_t)(bb * 2048 + tok)) * 1024 + hh*64 + mf*16 + g*4;
            *reinterpret_cast<bf4v*>(Oh + o) = hv;
            *reinterpret_cast<bf4v*>(Ol + o) = lv;
        }
    }
}

// ---------------------------------------------------------------- launch
extern "C" void kernel_launch(void* const* d_in, const int* in_sizes, int n_in,
                              void* d_out, int out_size, void* d_ws, size_t ws_size,
                              hipStream_t stream) {
    (void)in_sizes; (void)n_in; (void)out_size; (void)ws_size;
    const float* x      = (const float*)d_in[0];
    const float* w_qkv  = (const float*)d_in[1];
    const float* b_qkv  = (const float*)d_in[2];
    const float* w_proj = (const float*)d_in[3];
    const float* b_proj = (const float*)d_in[4];
    float* out = (float*)d_out;

    char* w = (char*)d_ws;
    // ws layout (bytes); total 151 MB. K/V regions are followed by other live
    // regions so the attn kernel's +<=4KB prefetch overread stays in-bounds.
    unsigned short* XH  = (unsigned short*)(w + 0);           // 16.78 MB [8192][1024]
    unsigned short* XL  = (unsigned short*)(w + 16777216);
    unsigned short* QH  = (unsigned short*)(w + 33554432);    // [B,H,2048,64]
    unsigned short* QL  = (unsigned short*)(w + 50331648);
    unsigned short* KH  = (unsigned short*)(w + 67108864);
    unsigned short* KL  = (unsigned short*)(w + 83886080);
    unsigned short* VTH = (unsigned short*)(w + 100663296);   // [B,H,64,2048] k-permuted
    unsigned short* VTL = (unsigned short*)(w + 117440512);
    unsigned short* WQH = (unsigned short*)(w + 134217728);   // 6.29 MB [3072][1024] (W^T)
    unsigned short* WQL = (unsigned short*)(w + 140509184);
    unsigned short* WPH = (unsigned short*)(w + 146800640);   // 2.10 MB [1024][1024] (W^T)
    unsigned short* WPL = (unsigned short*)(w + 148897792);
    unsigned short* ATH = XH;                                 // att out aliases X
    unsigned short* ATL = XL;

    split_rm<<<8192, 256, 0, stream>>>(x, XH, XL, 2097152);
    transpose_split<<<dim3(96, 32), 256, 0, stream>>>(w_qkv, WQH, WQL, 1024, 3072);
    transpose_split<<<dim3(32, 32), 256, 0, stream>>>(w_proj, WPH, WPL, 1024, 1024);
    gemm3k<0><<<dim3(24, 64), 256, 0, stream>>>(XH, XL, WQH, WQL, b_qkv, nullptr,
                                                QH, QL, KH, KL, VTH, VTL);
    attn<<<1024, 256, 0, stream>>>(QH, QL, KH, KL, VTH, VTL, ATH, ATL);
    gemm3k<1><<<dim3(8, 64), 256, 0, stream>>>(ATH, ATL, WPH, WPL, b_proj, out,
                                               nullptr, nullptr, nullptr, nullptr, nullptr, nullptr);
}